// Round 6
// baseline (253.965 us; speedup 1.0000x reference)
//
#include <hip/hip_runtime.h>
#include <hip/hip_bf16.h>

// out[M=131072, N=512] = x[M, K=512] @ W^T[N=512, K=512] + bias[N]
// fp32 in/out; bf16 MFMA (fp32 accum).
//
// Kernel 1: repack W fp32 -> bf16 MFMA-fragment layout in d_ws (512 KB).
// Kernel 2: PERSISTENT GEMM. 256 blocks (exactly 1/CU, LDS=128KB), each owns
//   8 consecutive 64-row tiles. Per tile: issue next tile's A global loads
//   (regs) FIRST -> barrier-free unrolled 16-step K-loop (MFMA on LDS A +
//   L2-resident repacked B) -> convert+ds_write next tile into other LDS
//   buffer -> this tile's stores -> raw lgkmcnt(0)+s_barrier (NO vmcnt
//   drain: store burst of tile t and load burst of t+1 overlap t+1 compute).
//   Goal: continuous HBM streaming instead of per-block burst/idle phases
//   (rounds 2-5 all ~2.2x memory roofline with every pipe <40% busy).
//   1024 thr = 16 waves (4/SIMD), wave tile 64x32, ~110 regs, no spill.

#define M_TOTAL 131072
#define KDIM 512
#define NDIM 512
#define BM 64
#define NKSTEP 16
#define NT 8
#define NBLK 256

typedef __attribute__((ext_vector_type(8))) short bf16x8;
typedef __attribute__((ext_vector_type(4))) float f32x4;
typedef __attribute__((ext_vector_type(4))) float fv4;
typedef __attribute__((ext_vector_type(4))) int iv4;

__device__ __forceinline__ unsigned short f2bf(float f) {
    union { float f; unsigned u; } c; c.f = f;
    unsigned r = c.u + 0x7fffu + ((c.u >> 16) & 1u);  // RNE
    return (unsigned short)(r >> 16);
}

__device__ __forceinline__ iv4 pack8(fv4 lo, fv4 hi) {
    union { unsigned short us[8]; iv4 v; } p;
#pragma unroll
    for (int i = 0; i < 4; ++i) { p.us[i] = f2bf(lo[i]); p.us[4 + i] = f2bf(hi[i]); }
    return p.v;
}

// wf[((t*16+kb)*64 + l)*8 + j] = bf16( W[t*16 + (l&15)][kb*32 + (l>>4)*8 + j] )
__global__ void repack_w_kernel(const float* __restrict__ w,
                                unsigned short* __restrict__ wf) {
    const int gtid = blockIdx.x * 256 + threadIdx.x;  // 0..32767
    const int tk = gtid >> 6;   // t*16 + kb
    const int l  = gtid & 63;
    const int n  = (tk >> 4) * 16 + (l & 15);
    const int k0 = (tk & 15) * 32 + (l >> 4) * 8;
    const fv4* src = reinterpret_cast<const fv4*>(w + n * KDIM + k0);
    *reinterpret_cast<iv4*>(wf + tk * 512 + l * 8) = pack8(src[0], src[1]);
}

__global__ __launch_bounds__(1024, 4) void linear_bf16_kernel(
    const float* __restrict__ x, const unsigned short* __restrict__ wf,
    const float* __restrict__ bias, float* __restrict__ out) {
    // per buffer: 64 rows x 512 cols bf16, 16B-chunk swizzled:
    //   ushort idx = row*512 + ((chunk ^ (row&7))<<3) + (col&7), chunk=col>>3
    __shared__ __attribute__((aligned(16))) unsigned short lds_a[2][BM * KDIM];  // 2x64KB

    const int tid  = threadIdx.x;
    const int lane = tid & 63;
    const int wcol = tid >> 6;   // 0..15 -> 32-col block
    const int fr   = lane & 15;
    const int fc   = lane >> 4;  // k-chunk 0..3

    // ---- staging coords: thread -> row tid>>4, chunk stripe tid&15 ----
    const int srow = tid >> 4;   // 0..63
    const int q    = tid & 15;   // 0..15
    const int skey = (srow & 7) << 3;

    // ---- B fragment base: per-lane ptr into repacked W (L2-resident) ----
    const unsigned short* wfbase = wf + (wcol * 32) * 512 + lane * 8;
    const int akey = (fr & 7) << 3;  // row&7 invariant under +m*16

    float bv[2];
#pragma unroll
    for (int n = 0; n < 2; ++n)
        bv[n] = bias[wcol * 32 + n * 16 + fr];

    fv4 st[8];

    auto LOADT = [&](int tile) {
        const float* xrow =
            x + (size_t)((blockIdx.x * NT + tile) * BM + srow) * KDIM;
#pragma unroll
        for (int i = 0; i < 4; ++i) {
            const fv4* src = reinterpret_cast<const fv4*>(xrow + (i * 16 + q) * 8);
            st[2 * i]     = src[0];
            st[2 * i + 1] = src[1];
        }
    };
    auto WRITET = [&](int buf) {
#pragma unroll
        for (int i = 0; i < 4; ++i) {
            const int c = i * 16 + q;
            *reinterpret_cast<iv4*>(&lds_a[buf][srow * 512 + ((c << 3) ^ skey)]) =
                pack8(st[2 * i], st[2 * i + 1]);
        }
    };

    // ---- prologue: stage tile 0 ----
    LOADT(0);
    WRITET(0);
    __syncthreads();

    for (int t = 0; t < NT; ++t) {
        const int cur = t & 1;
        if (t + 1 < NT) LOADT(t + 1);  // HBM read burst issues under compute

        f32x4 acc[4][2];
#pragma unroll
        for (int m = 0; m < 4; ++m)
#pragma unroll
            for (int n = 0; n < 2; ++n)
                acc[m][n] = (f32x4){0.f, 0.f, 0.f, 0.f};

        // ---- K-loop: 16 unrolled steps, no barriers ----
#pragma unroll
        for (int kb = 0; kb < NKSTEP; ++kb) {
            bf16x8 bfv[2];
#pragma unroll
            for (int n = 0; n < 2; ++n)
                bfv[n] = *reinterpret_cast<const bf16x8*>(wfbase + (n * 16 + kb) * 512);
            bf16x8 af[4];
#pragma unroll
            for (int m = 0; m < 4; ++m)
                af[m] = *reinterpret_cast<const bf16x8*>(
                    &lds_a[cur][(m * 16 + fr) * 512 + (((kb * 4 + fc) << 3) ^ akey)]);
#pragma unroll
            for (int n = 0; n < 2; ++n)
#pragma unroll
                for (int m = 0; m < 4; ++m)
                    acc[m][n] = __builtin_amdgcn_mfma_f32_16x16x32_bf16(
                        af[m], bfv[n], acc[m][n], 0, 0, 0);
        }

        if (t + 1 < NT) WRITET(cur ^ 1);  // convert + ds_write next tile

        // ---- this tile's stores (stay in flight past the raw barrier) ----
        const int rowbase = (blockIdx.x * NT + t) * BM;
        float* obase = out + (size_t)(rowbase + fc * 4) * NDIM + wcol * 32 + fr;
#pragma unroll
        for (int m = 0; m < 4; ++m)
#pragma unroll
            for (int j = 0; j < 4; ++j) {
                float* orow = obase + (m * 16 + j) * NDIM;
#pragma unroll
                for (int n = 0; n < 2; ++n)
                    orow[n * 16] = acc[m][n][j] + bv[n];
            }

        if (t + 1 < NT) {
            asm volatile("s_waitcnt lgkmcnt(0)" ::: "memory");  // ds_writes done
            __builtin_amdgcn_s_barrier();  // no vmcnt drain: loads/stores fly on
        }
    }
}

extern "C" void kernel_launch(void* const* d_in, const int* in_sizes, int n_in,
                              void* d_out, int out_size, void* d_ws, size_t ws_size,
                              hipStream_t stream) {
    const float* x    = (const float*)d_in[0];
    const float* w    = (const float*)d_in[1];
    const float* bias = (const float*)d_in[2];
    float* out        = (float*)d_out;
    unsigned short* wf = (unsigned short*)d_ws;  // 512 KB

    hipLaunchKernelGGL(repack_w_kernel, dim3(128), dim3(256), 0, stream, w, wf);
    hipLaunchKernelGGL(linear_bf16_kernel, dim3(NBLK), dim3(1024), 0, stream,
                       x, wf, bias, out);
}

// Round 7
// 149.462 us; speedup vs baseline: 1.6992x; 1.6992x over previous
//
#include <hip/hip_runtime.h>
#include <hip/hip_bf16.h>

// out[M=131072, N=512] = x[M, K=512] @ W^T[N=512, K=512] + bias[N]
// fp32 in/out; bf16 MFMA (fp32 accum).
//
// Kernel 1: repack W fp32 -> bf16 MFMA-fragment layout in d_ws (512 KB).
// Kernel 2: GEMM, r4 geometry (BM=64, 512 thr = 8 waves 1x8, wave 64x64,
//   BK=32 double-buffered LDS A, verified swizzle/epilogue) with the round-7
//   fix: DEEP REGISTER PIPELINING. Rounds 1-6 all ran at 128 regs/wave
//   (64 VGPR + 64 AGPR) -- zero headroom to pipeline loads, so every K-step
//   exposed full L2/HBM latency serially (all pipes <40% busy in every
//   profile). Now: 8-deep x-prefetch ring (32 VGPR), B-fragments prefetched
//   1 step ahead into double-buffered regs (32 VGPR), and raw
//   lgkmcnt(0)+s_barrier per step so the compiler's COUNTED vmcnt keeps up
//   to 8 x-loads in flight across barriers (__syncthreads would drain
//   vmcnt(0) and nullify the ring). Target ~170 regs/wave, 3 waves/SIMD.

#define M_TOTAL 131072
#define KDIM 512
#define NDIM 512
#define BM 64
#define BK 32
#define NKSTEP 16

typedef __attribute__((ext_vector_type(8))) short bf16x8;
typedef __attribute__((ext_vector_type(4))) float f32x4;
typedef __attribute__((ext_vector_type(4))) float fv4;
typedef __attribute__((ext_vector_type(4))) int iv4;
typedef __attribute__((ext_vector_type(2))) int iv2;

__device__ __forceinline__ unsigned short f2bf(float f) {
    union { float f; unsigned u; } c; c.f = f;
    unsigned r = c.u + 0x7fffu + ((c.u >> 16) & 1u);  // RNE
    return (unsigned short)(r >> 16);
}

__device__ __forceinline__ iv4 pack8(fv4 lo, fv4 hi) {
    union { unsigned short us[8]; iv4 v; } p;
#pragma unroll
    for (int i = 0; i < 4; ++i) { p.us[i] = f2bf(lo[i]); p.us[4 + i] = f2bf(hi[i]); }
    return p.v;
}

// wf[((t*16+kb)*64 + l)*8 + j] = bf16( W[t*16 + (l&15)][kb*32 + (l>>4)*8 + j] )
__global__ void repack_w_kernel(const float* __restrict__ w,
                                unsigned short* __restrict__ wf) {
    const int gtid = blockIdx.x * 256 + threadIdx.x;  // 0..32767
    const int tk = gtid >> 6;   // t*16 + kb
    const int l  = gtid & 63;
    const int n  = (tk >> 4) * 16 + (l & 15);
    const int k0 = (tk & 15) * 32 + (l >> 4) * 8;
    const fv4* src = reinterpret_cast<const fv4*>(w + n * KDIM + k0);
    *reinterpret_cast<iv4*>(wf + tk * 512 + l * 8) = pack8(src[0], src[1]);
}

__global__ __launch_bounds__(512) void linear_bf16_kernel(
    const float* __restrict__ x, const unsigned short* __restrict__ wf,
    const float* __restrict__ bias, float* __restrict__ out) {
    __shared__ __attribute__((aligned(16))) unsigned short lds_a[2][BM * BK];  // 2 x 4 KB

    const int tid  = threadIdx.x;
    const int lane = tid & 63;
    const int wcol = tid >> 6;   // 0..7 -> 64-col block
    const int fr   = lane & 15;
    const int fc   = lane >> 4;  // k-chunk 0..3

    const int rowbase = blockIdx.x * BM;

    // ---- A staging: thread t -> row t>>3 (0..63), 4-float quarter t&7 ----
    const int srow = tid >> 3;
    const int sq   = tid & 7;
    const float* xptr = x + (size_t)(rowbase + srow) * KDIM + sq * 4;
    // verified r4 swizzle (0 bank conflicts): 16B chunk c' = c ^ ((row>>1)&3)
    const int st_a = srow * BK + (((sq >> 1) ^ ((srow >> 1) & 3)) << 3) + (sq & 1) * 4;
    const int aoff = fr * BK + ((fc ^ ((fr >> 1) & 3)) << 3);

    // ---- B fragment base: per-lane ptr into repacked W (L2-resident) ----
    const unsigned short* wfrag = wf + lane * 8;

    f32x4 acc[4][4];
#pragma unroll
    for (int m = 0; m < 4; ++m)
#pragma unroll
        for (int n = 0; n < 4; ++n)
            acc[m][n] = (f32x4){0.f, 0.f, 0.f, 0.f};

    fv4 ra[8];        // 8-deep x ring (32 VGPR)
    bf16x8 bfv[2][4]; // B double buffer (32 VGPR)

    auto LOADA = [&](int slot, int kb) {
        ra[slot] = *reinterpret_cast<const fv4*>(xptr + kb * BK);
    };
    auto LOADB = [&](int pb, int kb) {
#pragma unroll
        for (int n = 0; n < 4; ++n)
            bfv[pb][n] = *reinterpret_cast<const bf16x8*>(
                wfrag + ((wcol * 4 + n) * 16 + kb) * 512);
    };
    auto WRITEA = [&](int buf, int slot) {
        union { unsigned short us[4]; iv2 v; } p;
#pragma unroll
        for (int i = 0; i < 4; ++i) p.us[i] = f2bf(ra[slot][i]);
        *reinterpret_cast<iv2*>(&lds_a[buf][st_a]) = p.v;
    };
    auto COMPUTE = [&](int buf, int pb) {
        bf16x8 af[4];
#pragma unroll
        for (int m = 0; m < 4; ++m)
            af[m] = *reinterpret_cast<const bf16x8*>(&lds_a[buf][aoff + m * 512]);
#pragma unroll
        for (int n = 0; n < 4; ++n)
#pragma unroll
            for (int m = 0; m < 4; ++m)
                acc[m][n] = __builtin_amdgcn_mfma_f32_16x16x32_bf16(
                    af[m], bfv[pb][n], acc[m][n], 0, 0, 0);
    };

    // ---- prologue: B(0) + 8-deep x ring; stage step-0 A ----
    LOADB(0, 0);
#pragma unroll
    for (int i = 0; i < 8; ++i) LOADA(i, i);
    WRITEA(0, 0);  // counted vmcnt: only ra[0]'s load drains; 7 stay in flight
    asm volatile("s_waitcnt lgkmcnt(0)" ::: "memory");
    __builtin_amdgcn_s_barrier();

#pragma unroll
    for (int kb = 0; kb < NKSTEP; ++kb) {
        if (kb + 8 < NKSTEP) LOADA(kb & 7, kb + 8);      // HBM issue, 8 ahead
        if (kb + 1 < NKSTEP) LOADB((kb + 1) & 1, kb + 1); // L2 issue, 1 ahead
        COMPUTE(kb & 1, kb & 1);
        if (kb + 1 < NKSTEP) WRITEA((kb + 1) & 1, (kb + 1) & 7);
        if (kb + 1 < NKSTEP) {
            asm volatile("s_waitcnt lgkmcnt(0)" ::: "memory");  // ds ops done
            __builtin_amdgcn_s_barrier();  // NO vmcnt drain: ring stays in flight
        }
    }

    // ---- epilogue: bias + store (verified r4/r5 layout) ----
    float bv[4];
#pragma unroll
    for (int n = 0; n < 4; ++n)
        bv[n] = bias[wcol * 64 + n * 16 + fr];

    float* obase = out + (size_t)(rowbase + fc * 4) * NDIM + wcol * 64 + fr;
#pragma unroll
    for (int m = 0; m < 4; ++m)
#pragma unroll
        for (int j = 0; j < 4; ++j) {
            float* orow = obase + (m * 16 + j) * NDIM;
#pragma unroll
            for (int n = 0; n < 4; ++n)
                orow[n * 16] = acc[m][n][j] + bv[n];
        }
}

extern "C" void kernel_launch(void* const* d_in, const int* in_sizes, int n_in,
                              void* d_out, int out_size, void* d_ws, size_t ws_size,
                              hipStream_t stream) {
    const float* x    = (const float*)d_in[0];
    const float* w    = (const float*)d_in[1];
    const float* bias = (const float*)d_in[2];
    float* out        = (float*)d_out;
    unsigned short* wf = (unsigned short*)d_ws;  // 512 KB

    hipLaunchKernelGGL(repack_w_kernel, dim3(128), dim3(256), 0, stream, w, wf);
    hipLaunchKernelGGL(linear_bf16_kernel, dim3(M_TOTAL / BM), dim3(512), 0, stream,
                       x, wf, bias, out);
}

// Round 8
// 140.618 us; speedup vs baseline: 1.8061x; 1.0629x over previous
//
#include <hip/hip_runtime.h>
#include <hip/hip_bf16.h>

// out[M=131072, N=512] = x[M, K=512] @ W^T[N=512, K=512] + bias[N]
// fp32 in/out; bf16 MFMA (fp32 accum).
//
// Kernel 1: repack W fp32 -> bf16 MFMA-fragment layout in d_ws (512 KB).
// Kernel 2: GEMM. Round-8: acc was the register bind (64 acc + pipeline regs
//   > 128 cliff -> rounds 2-7 had EITHER 4 waves/SIMD or pipeline regs,
//   never both; measured time ~= SUM of HBM/L2-B/MFMA phases, no overlap).
//   Now: wave tile 64x32 (acc=32), 8 waves (1x8) x TWO N-passes over the
//   same full-K LDS A-tile (r5-verified 64KB layout+swizzle, staged once,
//   ONE barrier) -> BN=512 per block (x read once), B-amortization unchanged.
//   ~95-110 regs -> 2 blocks/CU, 4 waves/SIMD, AND B double-buffer + 32-step
//   fully-unrolled barrier-free main loop.

#define M_TOTAL 131072
#define KDIM 512
#define NDIM 512
#define BM 64
#define NKSTEP 16

typedef __attribute__((ext_vector_type(8))) short bf16x8;
typedef __attribute__((ext_vector_type(4))) float f32x4;
typedef __attribute__((ext_vector_type(4))) float fv4;
typedef __attribute__((ext_vector_type(4))) int iv4;

__device__ __forceinline__ unsigned short f2bf(float f) {
    union { float f; unsigned u; } c; c.f = f;
    unsigned r = c.u + 0x7fffu + ((c.u >> 16) & 1u);  // RNE
    return (unsigned short)(r >> 16);
}

__device__ __forceinline__ iv4 pack8(fv4 lo, fv4 hi) {
    union { unsigned short us[8]; iv4 v; } p;
#pragma unroll
    for (int i = 0; i < 4; ++i) { p.us[i] = f2bf(lo[i]); p.us[4 + i] = f2bf(hi[i]); }
    return p.v;
}

// wf[((t*16+kb)*64 + l)*8 + j] = bf16( W[t*16 + (l&15)][kb*32 + (l>>4)*8 + j] )
__global__ void repack_w_kernel(const float* __restrict__ w,
                                unsigned short* __restrict__ wf) {
    const int gtid = blockIdx.x * 256 + threadIdx.x;  // 0..32767
    const int tk = gtid >> 6;   // t*16 + kb
    const int l  = gtid & 63;
    const int n  = (tk >> 4) * 16 + (l & 15);
    const int k0 = (tk & 15) * 32 + (l >> 4) * 8;
    const fv4* src = reinterpret_cast<const fv4*>(w + n * KDIM + k0);
    *reinterpret_cast<iv4*>(wf + tk * 512 + l * 8) = pack8(src[0], src[1]);
}

__global__ __launch_bounds__(512, 4) void linear_bf16_kernel(
    const float* __restrict__ x, const unsigned short* __restrict__ wf,
    const float* __restrict__ bias, float* __restrict__ out) {
    // 64 rows x 512 cols bf16, 16B-chunk swizzled (r5-verified):
    //   ushort idx = row*512 + ((chunk ^ (row&7))<<3) + (col&7), chunk=col>>3
    __shared__ __attribute__((aligned(16))) unsigned short lds_a[BM * KDIM];  // 64 KB

    const int tid  = threadIdx.x;
    const int lane = tid & 63;
    const int wc   = tid >> 6;   // 0..7 -> 32-col strip (per pass)
    const int fr   = lane & 15;
    const int fc   = lane >> 4;  // k-chunk 0..3

    const int rowbase = blockIdx.x * BM;

    // ---- prologue: stage full A-tile (r5-verified), ONE barrier ----
    {
        const int srow = tid >> 3;   // 0..63
        const int q    = tid & 7;
        const float* xrow = x + (size_t)(rowbase + srow) * KDIM;
        const int key = (srow & 7) << 3;
#pragma unroll
        for (int i = 0; i < 8; ++i) {
            const int c = i * 8 + q;             // 16B chunk 0..63
            const fv4* src = reinterpret_cast<const fv4*>(xrow + c * 8);
            *reinterpret_cast<iv4*>(&lds_a[srow * 512 + ((c << 3) ^ key)]) =
                pack8(src[0], src[1]);
        }
    }
    __syncthreads();

    const int akey = (fr & 7) << 3;  // row&7 invariant under +m*16

    f32x4 acc[4][2];
#pragma unroll
    for (int m = 0; m < 4; ++m)
#pragma unroll
        for (int n = 0; n < 2; ++n)
            acc[m][n] = (f32x4){0.f, 0.f, 0.f, 0.f};

    bf16x8 bfv[2][2];  // B double buffer (16 VGPR)
    // linear step s = p*16 + kb; pass p covers cols p*256 + wc*32 .. +32
    auto LOADB = [&](int buf, int s) {
        const int p = s >> 4, kb = s & 15;
#pragma unroll
        for (int n = 0; n < 2; ++n)
            bfv[buf][n] = *reinterpret_cast<const bf16x8*>(
                wf + (size_t)(((p * 16 + wc * 2 + n) * 16 + kb) * 512) + lane * 8);
    };

    LOADB(0, 0);

#pragma unroll
    for (int s = 0; s < 32; ++s) {
        const int kb = s & 15;
        if (s + 1 < 32) LOADB((s + 1) & 1, s + 1);  // L2 prefetch, 1 ahead

        bf16x8 af[4];
#pragma unroll
        for (int m = 0; m < 4; ++m)
            af[m] = *reinterpret_cast<const bf16x8*>(
                &lds_a[(m * 16 + fr) * 512 + (((kb * 4 + fc) << 3) ^ akey)]);
#pragma unroll
        for (int n = 0; n < 2; ++n)
#pragma unroll
            for (int m = 0; m < 4; ++m)
                acc[m][n] = __builtin_amdgcn_mfma_f32_16x16x32_bf16(
                    af[m], bfv[s & 1][n], acc[m][n], 0, 0, 0);

        if (kb == 15) {
            // ---- end of pass p: bias + store this pass's 64x32 strip ----
            const int p = s >> 4;
            const int colbase = p * 256 + wc * 32;
            float bv[2];
#pragma unroll
            for (int n = 0; n < 2; ++n)
                bv[n] = bias[colbase + n * 16 + fr];
            float* obase = out + (size_t)(rowbase + fc * 4) * NDIM + colbase + fr;
#pragma unroll
            for (int m = 0; m < 4; ++m)
#pragma unroll
                for (int j = 0; j < 4; ++j) {
                    float* orow = obase + (m * 16 + j) * NDIM;
#pragma unroll
                    for (int n = 0; n < 2; ++n)
                        orow[n * 16] = acc[m][n][j] + bv[n];
                }
#pragma unroll
            for (int m = 0; m < 4; ++m)
#pragma unroll
                for (int n = 0; n < 2; ++n)
                    acc[m][n] = (f32x4){0.f, 0.f, 0.f, 0.f};
        }
    }
}

extern "C" void kernel_launch(void* const* d_in, const int* in_sizes, int n_in,
                              void* d_out, int out_size, void* d_ws, size_t ws_size,
                              hipStream_t stream) {
    const float* x    = (const float*)d_in[0];
    const float* w    = (const float*)d_in[1];
    const float* bias = (const float*)d_in[2];
    float* out        = (float*)d_out;
    unsigned short* wf = (unsigned short*)d_ws;  // 512 KB

    hipLaunchKernelGGL(repack_w_kernel, dim3(128), dim3(256), 0, stream, w, wf);
    hipLaunchKernelGGL(linear_bf16_kernel, dim3(M_TOTAL / BM), dim3(512), 0, stream,
                       x, wf, bias, out);
}